// Round 11
// baseline (254.810 us; speedup 1.0000x reference)
//
#include <hip/hip_runtime.h>

// GNN_Critic: 2-layer SAGEConv (F: 1 -> 16 -> 1) + global_add_pool.
//
// Round-15: machinery-free partition. r8-r14 profiles pin partition at
// 61-63us, 3x any other kernel; claim-padding null (r13) killed the
// contention theory -> the cost is the ring/claim/barrier flush machinery
// itself (3 barriers/round draining scattered stores + cross-XCD claims).
// This round deletes it: fixed 512-block grid, each (cell, block) owns a
// PRIVATE 128-word segment; insert = LDS cursor atomicAdd + one direct
// global store. No rings, no global claims, no barriers in the main loop,
// no shared lines (no ping-pong). Per-block lens -> blockCnt[cell][512]
// (coalesced on read). Overflow >128 (>=15 sigma for lambda=25) spills to
// a global list scanned by the bins (normally empty) -- same guarantee
// class as previous caps. Bins read 512 short segments/cell, one wave per
// segment. bin1/node1/pool/finalize otherwise r14-identical (absmax 4.0
// passing vs bf16 threshold 16.48).

#define BLK       1024
#define TILE      (BLK * 4)     // 4096 edges per partition sub-tile
#define NBLK      512           // partition grid (fixed; cell<<9 | bid)
#define CAPB      128           // words per (cell, block) segment
#define NSB       25            // src buckets
#define SBSH      13            // 8192-node window (32 KB)
#define WMSK      8191u
#define OVFCAP    (1u << 21)    // overflow list capacity (u64 entries)
#define CNT_ONE   (1u << 25)    // count field bits [31:25]
#define FX_BIAS   131072        // 2^17 per-add bias keeps sum field positive
#define SCALE     4096.0f       // 2^12 fixed-point scale
#define INV_SCALE (1.0f / 4096.0f)
#define IDQ       8388608.0f    // invdeg quantization scale (2^23)

// ---------------------------------------------------------------------------
// Partition: direct scatter into private (cell, block) segments.
// Prologue: pre-quantize x into xq1.
__global__ __launch_bounds__(BLK) void partition_kernel(
    const int* __restrict__ ei, const float* __restrict__ x,
    unsigned* __restrict__ xq1, unsigned* __restrict__ pairs,
    unsigned* __restrict__ blockCnt, unsigned long long* __restrict__ ovf,
    unsigned* __restrict__ ovfTail, int E, int N, int bins, unsigned Mdiv,
    int nc) {
    __shared__ unsigned cur[NBLK];        // per-cell cursors (nc = 500 used)
    const int tid = threadIdx.x;
    const unsigned bid = blockIdx.x;      // < NBLK by construction
    for (int j = tid; j < nc; j += BLK) cur[j] = 0;

    // pre-quantize payload for bin1
    for (int n = (int)bid * BLK + tid; n < N; n += NBLK * BLK)
        xq1[n] = CNT_ONE + (unsigned)((int)rintf(x[n] * SCALE) + FX_BIAS);
    __syncthreads();

    const int ntiles = (E + TILE - 1) / TILE;
    for (int t = (int)bid; t < ntiles; t += NBLK) {
        int e0 = t * TILE + tid * 4;
        int nv = E - e0; nv = nv < 0 ? 0 : (nv > 4 ? 4 : nv);
        int srcv[4], dstv[4];
        if (nv == 4 && ((E & 3) == 0)) {
            int4 s = *(const int4*)(ei + e0);
            int4 d = *(const int4*)(ei + E + e0);
            srcv[0] = s.x; srcv[1] = s.y; srcv[2] = s.z; srcv[3] = s.w;
            dstv[0] = d.x; dstv[1] = d.y; dstv[2] = d.z; dstv[3] = d.w;
        } else {
            for (int j = 0; j < nv; ++j) { srcv[j] = ei[e0 + j]; dstv[j] = ei[E + e0 + j]; }
        }
        for (int j = 0; j < 4; ++j) {
            if (j < nv) {
                unsigned dst = (unsigned)dstv[j];
                unsigned src = (unsigned)srcv[j];
                unsigned pt = (unsigned)(((unsigned long long)dst * Mdiv) >> 32);
                int ld = (int)dst - (int)pt * bins;
                while (ld >= bins) { ld -= bins; ++pt; }
                while (ld < 0)     { ld += bins; --pt; }
                unsigned cell = pt * NSB + (src >> SBSH);
                unsigned w = ((src & WMSK) << 14) | (unsigned)ld;
                unsigned idx = atomicAdd(&cur[cell], 1u);
                if (idx < CAPB) {
                    pairs[((((size_t)cell << 9) | bid) << 7) + idx] = w;
                } else {
                    unsigned ot = atomicAdd(ovfTail, 1u);
                    if (ot < OVFCAP)
                        ovf[ot] = ((unsigned long long)cell << 32) | w;
                }
            }
        }
    }
    __syncthreads();
    for (int j = tid; j < nc; j += BLK) {
        unsigned c = cur[j]; if (c > CAPB) c = CAPB;
        blockCnt[((size_t)j << 9) | bid] = c;
    }
}

// ---------------------------------------------------------------------------
// Bin pass 1: one block per cell. LDS = xq1 window + bins. Reads NBLK short
// segments (one wave per segment, lens LDS-broadcast) + overflow scan.
// Flush = plain stores to slab[sb][N].
__global__ __launch_bounds__(BLK, 8) void bin1_kernel(
    const unsigned* __restrict__ pairs, const unsigned* __restrict__ blockCnt,
    const unsigned long long* __restrict__ ovf,
    const unsigned* __restrict__ ovfTail,
    const unsigned* __restrict__ xq1, unsigned* __restrict__ slab,
    int N, int bins) {
    extern __shared__ unsigned sm[];
    unsigned* xs = sm;                   // [8192] window
    unsigned* sb = sm + 8192;            // [bins]
    __shared__ unsigned scnt[NBLK];
    const int tid = threadIdx.x;
    const int cell = blockIdx.x;
    const int p = cell / NSB;
    const int sbk = cell - p * NSB;
    const int wb = sbk << SBSH;
    int nn = N - wb; if (nn > 8192) nn = 8192;
    for (int j = tid; j < nn; j += BLK) xs[j] = xq1[wb + j];
    for (int j = tid; j < bins; j += BLK) sb[j] = 0;
    for (int j = tid; j < NBLK; j += BLK) scnt[j] = blockCnt[((size_t)cell << 9) + j];
    __syncthreads();
    {
        int wv6 = tid >> 6, lane = tid & 63;
        for (int s = wv6; s < NBLK; s += 16) {
            int len = (int)scnt[s];
            const unsigned* sp = pairs + ((((size_t)cell << 9) | (unsigned)s) << 7);
            for (int jj = lane; jj < len; jj += 64) {
                unsigned w = sp[jj];
                atomicAdd(&sb[w & 16383u], xs[w >> 14]);
            }
        }
    }
    {
        unsigned ot = *ovfTail; if (ot > OVFCAP) ot = OVFCAP;
        for (unsigned e = tid; e < ot; e += BLK) {
            unsigned long long pk = ovf[e];
            if ((unsigned)(pk >> 32) == (unsigned)cell) {
                unsigned w = (unsigned)pk;
                atomicAdd(&sb[w & 16383u], xs[w >> 14]);
            }
        }
    }
    __syncthreads();
    unsigned* dst = slab + (size_t)sbk * N + (size_t)p * bins;
    int nb = N - p * bins; if (nb > bins) nb = bins;
    for (int j = tid; j < nb; j += BLK) dst[j] = sb[j];
}

// ---------------------------------------------------------------------------
// Node pass 1 (r14): slab reduce -> (deg, mean1); h = relu(...);
// pvq = fix(h.W2l); zd = batch<<23 | q23(1/max(deg,1)); pool qv+b2 by graph.
__global__ void node_pass1_kernel(const float* __restrict__ x,
                                  const unsigned* __restrict__ slab,
                                  const float* __restrict__ W1l,
                                  const float* __restrict__ b1,
                                  const float* __restrict__ W1r,
                                  const float* __restrict__ W2l,
                                  const float* __restrict__ W2r,
                                  const float* __restrict__ b2,
                                  const int* __restrict__ batch,
                                  int* __restrict__ pvq,
                                  unsigned* __restrict__ zd,
                                  float* __restrict__ out,
                                  int N) {
    __shared__ float s_w1l[16], s_b1[16], s_w1r[16], s_w2l[16], s_w2r[16];
    if (threadIdx.x < 16) {
        s_w1l[threadIdx.x] = W1l[threadIdx.x];
        s_b1[threadIdx.x]  = b1[threadIdx.x];
        s_w1r[threadIdx.x] = W1r[threadIdx.x];
        s_w2l[threadIdx.x] = W2l[threadIdx.x];
        s_w2r[threadIdx.x] = W2r[threadIdx.x];
    }
    __syncthreads();
    int n = blockIdx.x * blockDim.x + threadIdx.x;
    float b2v = b2[0];
    float val = 0.0f;
    int g;
    if (n < N) {
        unsigned cnt = 0, fx = 0;
#pragma unroll
        for (int c = 0; c < NSB; ++c) {
            unsigned w = slab[(size_t)c * N + n];
            cnt += w >> 25;
            fx  += w & (CNT_ONE - 1);
        }
        float dg  = (float)cnt;
        float sum = (float)(int)(fx - cnt * (unsigned)FX_BIAS) * INV_SCALE;
        float m   = sum / fmaxf(dg, 1.0f);

        float xv = x[n];
        float pa = 0.0f, qa = 0.0f;
#pragma unroll
        for (int f = 0; f < 16; ++f) {
            float h = fmaf(m, s_w1l[f], fmaf(xv, s_w1r[f], s_b1[f]));
            h = fmaxf(h, 0.0f);
            pa = fmaf(h, s_w2l[f], pa);
            qa = fmaf(h, s_w2r[f], qa);
        }
        pvq[n] = (int)rintf(pa * SCALE);
        float invd = 1.0f / fmaxf(dg, 1.0f);
        unsigned q = (unsigned)rintf(invd * IDQ);
        if (q > 8388607u) q = 8388607u;
        g = batch[n];
        zd[n] = ((unsigned)g << 23) | q;
        val = qa + b2v;
    } else {
        g = batch[N - 1];  // pad lanes contribute 0 to a valid graph id
    }
    int g0 = __shfl(g, 0);
    unsigned long long same = __ballot(g == g0);
    if (same == ~0ULL) {
        for (int off = 32; off > 0; off >>= 1) val += __shfl_down(val, off);
        if ((threadIdx.x & 63) == 0) atomicAdd(&out[g0], val);
    } else {
        atomicAdd(&out[g], val);
    }
}

// ---------------------------------------------------------------------------
// Pool pass (r14 math, segment reads): accumulate pvq[src]*invdeg[dst] into
// per-graph i64 LDS bins; flush via u64 atomics into outq[512].
__global__ __launch_bounds__(BLK, 8) void pool_kernel(
    const unsigned* __restrict__ pairs, const unsigned* __restrict__ blockCnt,
    const unsigned long long* __restrict__ ovf,
    const unsigned* __restrict__ ovfTail,
    const int* __restrict__ pvq, const unsigned* __restrict__ zd,
    unsigned long long* __restrict__ outq,
    int N, int bins) {
    extern __shared__ unsigned sm[];
    int* ps = (int*)sm;                                   // [8192] pvq window
    unsigned* zs = sm + 8192;                             // [bins] zd part
    unsigned long long* gbin =
        (unsigned long long*)(sm + 8192 + 10000);         // [512] (8B aligned)
    __shared__ unsigned scnt[NBLK];
    const int tid = threadIdx.x;
    const int cell = blockIdx.x;
    const int p = cell / NSB;
    const int sbk = cell - p * NSB;
    const int wb = sbk << SBSH;
    int nn = N - wb; if (nn > 8192) nn = 8192;
    for (int j = tid; j < nn; j += BLK) ps[j] = pvq[wb + j];
    int nb = N - p * bins; if (nb > bins) nb = bins;
    for (int j = tid; j < nb; j += BLK) zs[j] = zd[(size_t)p * bins + j];
    for (int j = tid; j < NBLK; j += BLK) scnt[j] = blockCnt[((size_t)cell << 9) + j];
    if (tid < 512) gbin[tid] = 0ULL;
    __syncthreads();
    {
        int wv6 = tid >> 6, lane = tid & 63;
        for (int s = wv6; s < NBLK; s += 16) {
            int len = (int)scnt[s];
            const unsigned* sp = pairs + ((((size_t)cell << 9) | (unsigned)s) << 7);
            for (int jj = lane; jj < len; jj += 64) {
                unsigned w = sp[jj];
                unsigned z = zs[w & 16383u];
                int t = (int)rintf((float)ps[w >> 14] *
                                   ((float)(z & 0x7FFFFFu) * (1.0f / IDQ)));
                atomicAdd(&gbin[z >> 23], (unsigned long long)(long long)t);
            }
        }
    }
    {
        unsigned ot = *ovfTail; if (ot > OVFCAP) ot = OVFCAP;
        for (unsigned e = tid; e < ot; e += BLK) {
            unsigned long long pk = ovf[e];
            if ((unsigned)(pk >> 32) == (unsigned)cell) {
                unsigned w = (unsigned)pk;
                unsigned z = zs[w & 16383u];
                int t = (int)rintf((float)ps[w >> 14] *
                                   ((float)(z & 0x7FFFFFu) * (1.0f / IDQ)));
                atomicAdd(&gbin[z >> 23], (unsigned long long)(long long)t);
            }
        }
    }
    __syncthreads();
    if (tid < 512) {
        unsigned long long v = gbin[tid];
        if (v) atomicAdd(&outq[tid], v);
    }
}

// ---------------------------------------------------------------------------
// Finalize: out[g] += outq[g] / SCALE.
__global__ void finalize_kernel(const unsigned long long* __restrict__ outq,
                                float* __restrict__ out, int B) {
    int g = blockIdx.x * blockDim.x + threadIdx.x;
    if (g < B)
        out[g] += (float)(long long)outq[g] * INV_SCALE;
}

// ---------------------------------------------------------------------------
extern "C" void kernel_launch(void* const* d_in, const int* in_sizes, int n_in,
                              void* d_out, int out_size, void* d_ws, size_t ws_size,
                              hipStream_t stream) {
    const float* x     = (const float*)d_in[0];
    const int*   ei    = (const int*)d_in[1];   // [2, E] flat: src then dst
    const int*   batch = (const int*)d_in[2];
    const float* W1l = (const float*)d_in[4];
    const float* b1  = (const float*)d_in[5];
    const float* W1r = (const float*)d_in[6];
    const float* W2l = (const float*)d_in[7];
    const float* b2  = (const float*)d_in[8];
    const float* W2r = (const float*)d_in[9];

    const int N = in_sizes[0];        // 200000
    const int E = in_sizes[1] / 2;    // 6400000
    float* out = (float*)d_out;       // [512]

    const int pp   = 20;                                      // dst parts
    const int bins = (N + pp - 1) / pp;                       // 10000 (exact)
    const int nc   = pp * NSB;                                // 500 cells
    const unsigned Mdiv =
        (unsigned)(((1ULL << 32) + (unsigned)bins - 1) / (unsigned)bins);

    // workspace (u32 words): pairs[nc*NBLK*CAPB] | slab[NSB][N] | pvq[N] |
    // zd[N] | xq1[N] | blockCnt[nc*NBLK] | ovf[OVFCAP u64] |
    // ovfTail[16] | outq[512 u64]
    unsigned* pairs = (unsigned*)d_ws;
    unsigned* slab1 = pairs + (size_t)nc * NBLK * CAPB;       // 32,768,000
    int*      pvq   = (int*)(slab1 + (size_t)NSB * N);
    unsigned* zd    = (unsigned*)(pvq + N);
    unsigned* xq1   = zd + N;
    unsigned* blockCnt = xq1 + N;
    unsigned long long* ovf =
        (unsigned long long*)(blockCnt + (size_t)nc * NBLK);
    unsigned* ovfTail = (unsigned*)(ovf + OVFCAP);
    unsigned long long* outq = (unsigned long long*)(ovfTail + 16);

    hipMemsetAsync(d_out, 0, (size_t)out_size * sizeof(float), stream);
    hipMemsetAsync(ovfTail, 0, (16 + 1024) * sizeof(unsigned), stream);

    const int binShmem  = (8192 + bins) * 4;            // 72768 B
    const int poolShmem = (8192 + bins) * 4 + 512 * 8;  // 76864 B
    hipFuncSetAttribute((const void*)bin1_kernel,
                        hipFuncAttributeMaxDynamicSharedMemorySize, binShmem);
    hipFuncSetAttribute((const void*)pool_kernel,
                        hipFuncAttributeMaxDynamicSharedMemorySize, poolShmem);

    const int NB = 256;
    int node_blocks = (N + NB - 1) / NB;

    partition_kernel<<<NBLK, BLK, 0, stream>>>(ei, x, xq1, pairs, blockCnt,
                                               ovf, ovfTail, E, N, bins,
                                               Mdiv, nc);
    bin1_kernel<<<nc, BLK, binShmem, stream>>>(pairs, blockCnt, ovf, ovfTail,
                                               xq1, slab1, N, bins);
    node_pass1_kernel<<<node_blocks, NB, 0, stream>>>(x, slab1, W1l, b1, W1r,
                                                      W2l, W2r, b2, batch,
                                                      pvq, zd, out, N);
    pool_kernel<<<nc, BLK, poolShmem, stream>>>(pairs, blockCnt, ovf, ovfTail,
                                                pvq, zd, outq, N, bins);
    finalize_kernel<<<(out_size + 255) / 256, 256, 0, stream>>>(outq, out,
                                                                out_size);
}

// Round 12
// 199.157 us; speedup vs baseline: 1.2794x; 1.2794x over previous
//
#include <hip/hip_runtime.h>

// GNN_Critic: 2-layer SAGEConv (F: 1 -> 16 -> 1) + global_add_pool.
//
// Round-16: claim-free partition with LDS-staged coalesced drains.
// r11 proved direct 4B scatter pays 3.6x line write-allocate (146MB, 100us);
// r12's rings kept writes coalesced (40MB) but carried ~460K cross-XCD
// claim RMWs. Hybrid: private per-(cell,block) 64-word segments (no claims,
// no shared lines) + LDS rings drained ONCE at the end (coalesced, 256B-
// aligned). Per block lambda=25 edges/cell -> RING=64 never fills
// (P>64 ~ 1e-10); statistical overflow spills to the r15-proven global
// list (scanned by bins, normally empty). No barriers/flush rounds in the
// main loop. Bins/pool read 512 short segments/cell (r15-proven shape).
// Everything else identical to r14 (212.8us best; absmax 4.0 < 16.48).

#define BLK       1024
#define TILE      (BLK * 4)     // 4096 edges per partition sub-tile
#define NBLK      512           // partition grid (cell<<9 | bid)
#define RING      64            // LDS ring = private segment size (words)
#define NSB       25            // src buckets
#define SBSH      13            // 8192-node window (32 KB)
#define WMSK      8191u
#define OVFCAP    (1u << 20)    // overflow list capacity (u64 entries)
#define CNT_ONE   (1u << 25)    // count field bits [31:25]
#define FX_BIAS   131072        // 2^17 per-add bias keeps sum field positive
#define SCALE     4096.0f       // 2^12 fixed-point scale
#define INV_SCALE (1.0f / 4096.0f)
#define IDQ       8388608.0f    // invdeg quantization scale (2^23)

// ---------------------------------------------------------------------------
// Partition: insert into per-cell LDS rings (no global claims, no mid-kernel
// flushes); single final coalesced drain into private (cell, block) segments.
// Prologue: pre-quantize x into xq1.
__global__ __launch_bounds__(BLK) void partition_kernel(
    const int* __restrict__ ei, const float* __restrict__ x,
    unsigned* __restrict__ xq1, unsigned* __restrict__ pairs,
    unsigned* __restrict__ blockCnt, unsigned long long* __restrict__ ovf,
    unsigned* __restrict__ ovfTail, int E, int N, int bins, unsigned Mdiv,
    int nc) {
    extern __shared__ unsigned buf[];     // [nc][RING] = 128000 B
    __shared__ unsigned cnt[512];         // per-cell cursors (nc = 500 used)
    const int tid = threadIdx.x;
    const unsigned bid = blockIdx.x;      // < NBLK
    for (int j = tid; j < nc; j += BLK) cnt[j] = 0;

    // pre-quantize payload for bin1
    for (int n = (int)bid * BLK + tid; n < N; n += NBLK * BLK)
        xq1[n] = CNT_ONE + (unsigned)((int)rintf(x[n] * SCALE) + FX_BIAS);
    __syncthreads();

    const int ntiles = (E + TILE - 1) / TILE;
    for (int t = (int)bid; t < ntiles; t += NBLK) {
        int e0 = t * TILE + tid * 4;
        int nv = E - e0; nv = nv < 0 ? 0 : (nv > 4 ? 4 : nv);
        int srcv[4], dstv[4];
        if (nv == 4 && ((E & 3) == 0)) {
            int4 s = *(const int4*)(ei + e0);
            int4 d = *(const int4*)(ei + E + e0);
            srcv[0] = s.x; srcv[1] = s.y; srcv[2] = s.z; srcv[3] = s.w;
            dstv[0] = d.x; dstv[1] = d.y; dstv[2] = d.z; dstv[3] = d.w;
        } else {
            for (int j = 0; j < nv; ++j) { srcv[j] = ei[e0 + j]; dstv[j] = ei[E + e0 + j]; }
        }
        for (int j = 0; j < 4; ++j) {
            if (j < nv) {
                unsigned dst = (unsigned)dstv[j];
                unsigned src = (unsigned)srcv[j];
                unsigned pt = (unsigned)(((unsigned long long)dst * Mdiv) >> 32);
                int ld = (int)dst - (int)pt * bins;
                while (ld >= bins) { ld -= bins; ++pt; }
                while (ld < 0)     { ld += bins; --pt; }
                unsigned cell = pt * NSB + (src >> SBSH);
                unsigned w = ((src & WMSK) << 14) | (unsigned)ld;
                unsigned idx = atomicAdd(&cnt[cell], 1u);
                if (idx < RING) {
                    buf[cell * RING + idx] = w;
                } else {
                    unsigned ot = atomicAdd(ovfTail, 1u);
                    if (ot < OVFCAP)
                        ovf[ot] = ((unsigned long long)cell << 32) | w;
                }
            }
        }
    }
    __syncthreads();
    // single coalesced drain: one wave per cell (strided), 256B-aligned dst
    {
        int wv6 = tid >> 6, lane = tid & 63;
        for (int r = wv6; r < nc; r += 16) {
            unsigned len = cnt[r]; if (len > RING) len = RING;
            unsigned* dp = pairs + ((((size_t)r << 9) | bid) << 6);
            for (unsigned jj = lane; jj < len; jj += 64)
                dp[jj] = buf[r * RING + jj];
            if (lane == 0) blockCnt[((size_t)r << 9) | bid] = len;
        }
    }
}

// ---------------------------------------------------------------------------
// Bin pass 1: one block per cell. LDS = xq1 window + bins. Reads NBLK short
// segments (one wave per segment, lens LDS-broadcast) + overflow scan.
// Flush = plain stores to slab[sb][N].
__global__ __launch_bounds__(BLK, 8) void bin1_kernel(
    const unsigned* __restrict__ pairs, const unsigned* __restrict__ blockCnt,
    const unsigned long long* __restrict__ ovf,
    const unsigned* __restrict__ ovfTail,
    const unsigned* __restrict__ xq1, unsigned* __restrict__ slab,
    int N, int bins) {
    extern __shared__ unsigned sm[];
    unsigned* xs = sm;                   // [8192] window
    unsigned* sb = sm + 8192;            // [bins]
    __shared__ unsigned scnt[NBLK];
    const int tid = threadIdx.x;
    const int cell = blockIdx.x;
    const int p = cell / NSB;
    const int sbk = cell - p * NSB;
    const int wb = sbk << SBSH;
    int nn = N - wb; if (nn > 8192) nn = 8192;
    for (int j = tid; j < nn; j += BLK) xs[j] = xq1[wb + j];
    for (int j = tid; j < bins; j += BLK) sb[j] = 0;
    for (int j = tid; j < NBLK; j += BLK) scnt[j] = blockCnt[((size_t)cell << 9) + j];
    __syncthreads();
    {
        int wv6 = tid >> 6, lane = tid & 63;
        for (int s = wv6; s < NBLK; s += 16) {
            int len = (int)scnt[s];
            const unsigned* sp = pairs + ((((size_t)cell << 9) | (unsigned)s) << 6);
            for (int jj = lane; jj < len; jj += 64) {
                unsigned w = sp[jj];
                atomicAdd(&sb[w & 16383u], xs[w >> 14]);
            }
        }
    }
    {
        unsigned ot = *ovfTail; if (ot > OVFCAP) ot = OVFCAP;
        for (unsigned e = tid; e < ot; e += BLK) {
            unsigned long long pk = ovf[e];
            if ((unsigned)(pk >> 32) == (unsigned)cell) {
                unsigned w = (unsigned)pk;
                atomicAdd(&sb[w & 16383u], xs[w >> 14]);
            }
        }
    }
    __syncthreads();
    unsigned* dst = slab + (size_t)sbk * N + (size_t)p * bins;
    int nb = N - p * bins; if (nb > bins) nb = bins;
    for (int j = tid; j < nb; j += BLK) dst[j] = sb[j];
}

// ---------------------------------------------------------------------------
// Node pass 1 (r14): slab reduce -> (deg, mean1); h = relu(...);
// pvq = fix(h.W2l); zd = batch<<23 | q23(1/max(deg,1)); pool qv+b2 by graph.
__global__ void node_pass1_kernel(const float* __restrict__ x,
                                  const unsigned* __restrict__ slab,
                                  const float* __restrict__ W1l,
                                  const float* __restrict__ b1,
                                  const float* __restrict__ W1r,
                                  const float* __restrict__ W2l,
                                  const float* __restrict__ W2r,
                                  const float* __restrict__ b2,
                                  const int* __restrict__ batch,
                                  int* __restrict__ pvq,
                                  unsigned* __restrict__ zd,
                                  float* __restrict__ out,
                                  int N) {
    __shared__ float s_w1l[16], s_b1[16], s_w1r[16], s_w2l[16], s_w2r[16];
    if (threadIdx.x < 16) {
        s_w1l[threadIdx.x] = W1l[threadIdx.x];
        s_b1[threadIdx.x]  = b1[threadIdx.x];
        s_w1r[threadIdx.x] = W1r[threadIdx.x];
        s_w2l[threadIdx.x] = W2l[threadIdx.x];
        s_w2r[threadIdx.x] = W2r[threadIdx.x];
    }
    __syncthreads();
    int n = blockIdx.x * blockDim.x + threadIdx.x;
    float b2v = b2[0];
    float val = 0.0f;
    int g;
    if (n < N) {
        unsigned cnt = 0, fx = 0;
#pragma unroll
        for (int c = 0; c < NSB; ++c) {
            unsigned w = slab[(size_t)c * N + n];
            cnt += w >> 25;
            fx  += w & (CNT_ONE - 1);
        }
        float dg  = (float)cnt;
        float sum = (float)(int)(fx - cnt * (unsigned)FX_BIAS) * INV_SCALE;
        float m   = sum / fmaxf(dg, 1.0f);

        float xv = x[n];
        float pa = 0.0f, qa = 0.0f;
#pragma unroll
        for (int f = 0; f < 16; ++f) {
            float h = fmaf(m, s_w1l[f], fmaf(xv, s_w1r[f], s_b1[f]));
            h = fmaxf(h, 0.0f);
            pa = fmaf(h, s_w2l[f], pa);
            qa = fmaf(h, s_w2r[f], qa);
        }
        pvq[n] = (int)rintf(pa * SCALE);
        float invd = 1.0f / fmaxf(dg, 1.0f);
        unsigned q = (unsigned)rintf(invd * IDQ);
        if (q > 8388607u) q = 8388607u;
        g = batch[n];
        zd[n] = ((unsigned)g << 23) | q;
        val = qa + b2v;
    } else {
        g = batch[N - 1];  // pad lanes contribute 0 to a valid graph id
    }
    int g0 = __shfl(g, 0);
    unsigned long long same = __ballot(g == g0);
    if (same == ~0ULL) {
        for (int off = 32; off > 0; off >>= 1) val += __shfl_down(val, off);
        if ((threadIdx.x & 63) == 0) atomicAdd(&out[g0], val);
    } else {
        atomicAdd(&out[g], val);
    }
}

// ---------------------------------------------------------------------------
// Pool pass (r14 math, segment reads): accumulate pvq[src]*invdeg[dst] into
// per-graph i64 LDS bins; flush via u64 atomics into outq[512].
__global__ __launch_bounds__(BLK, 8) void pool_kernel(
    const unsigned* __restrict__ pairs, const unsigned* __restrict__ blockCnt,
    const unsigned long long* __restrict__ ovf,
    const unsigned* __restrict__ ovfTail,
    const int* __restrict__ pvq, const unsigned* __restrict__ zd,
    unsigned long long* __restrict__ outq,
    int N, int bins) {
    extern __shared__ unsigned sm[];
    int* ps = (int*)sm;                                   // [8192] pvq window
    unsigned* zs = sm + 8192;                             // [bins] zd part
    unsigned long long* gbin =
        (unsigned long long*)(sm + 8192 + 10000);         // [512] (8B aligned)
    __shared__ unsigned scnt[NBLK];
    const int tid = threadIdx.x;
    const int cell = blockIdx.x;
    const int p = cell / NSB;
    const int sbk = cell - p * NSB;
    const int wb = sbk << SBSH;
    int nn = N - wb; if (nn > 8192) nn = 8192;
    for (int j = tid; j < nn; j += BLK) ps[j] = pvq[wb + j];
    int nb = N - p * bins; if (nb > bins) nb = bins;
    for (int j = tid; j < nb; j += BLK) zs[j] = zd[(size_t)p * bins + j];
    for (int j = tid; j < NBLK; j += BLK) scnt[j] = blockCnt[((size_t)cell << 9) + j];
    if (tid < 512) gbin[tid] = 0ULL;
    __syncthreads();
    {
        int wv6 = tid >> 6, lane = tid & 63;
        for (int s = wv6; s < NBLK; s += 16) {
            int len = (int)scnt[s];
            const unsigned* sp = pairs + ((((size_t)cell << 9) | (unsigned)s) << 6);
            for (int jj = lane; jj < len; jj += 64) {
                unsigned w = sp[jj];
                unsigned z = zs[w & 16383u];
                int t = (int)rintf((float)ps[w >> 14] *
                                   ((float)(z & 0x7FFFFFu) * (1.0f / IDQ)));
                atomicAdd(&gbin[z >> 23], (unsigned long long)(long long)t);
            }
        }
    }
    {
        unsigned ot = *ovfTail; if (ot > OVFCAP) ot = OVFCAP;
        for (unsigned e = tid; e < ot; e += BLK) {
            unsigned long long pk = ovf[e];
            if ((unsigned)(pk >> 32) == (unsigned)cell) {
                unsigned w = (unsigned)pk;
                unsigned z = zs[w & 16383u];
                int t = (int)rintf((float)ps[w >> 14] *
                                   ((float)(z & 0x7FFFFFu) * (1.0f / IDQ)));
                atomicAdd(&gbin[z >> 23], (unsigned long long)(long long)t);
            }
        }
    }
    __syncthreads();
    if (tid < 512) {
        unsigned long long v = gbin[tid];
        if (v) atomicAdd(&outq[tid], v);
    }
}

// ---------------------------------------------------------------------------
// Finalize: out[g] += outq[g] / SCALE.
__global__ void finalize_kernel(const unsigned long long* __restrict__ outq,
                                float* __restrict__ out, int B) {
    int g = blockIdx.x * blockDim.x + threadIdx.x;
    if (g < B)
        out[g] += (float)(long long)outq[g] * INV_SCALE;
}

// ---------------------------------------------------------------------------
extern "C" void kernel_launch(void* const* d_in, const int* in_sizes, int n_in,
                              void* d_out, int out_size, void* d_ws, size_t ws_size,
                              hipStream_t stream) {
    const float* x     = (const float*)d_in[0];
    const int*   ei    = (const int*)d_in[1];   // [2, E] flat: src then dst
    const int*   batch = (const int*)d_in[2];
    const float* W1l = (const float*)d_in[4];
    const float* b1  = (const float*)d_in[5];
    const float* W1r = (const float*)d_in[6];
    const float* W2l = (const float*)d_in[7];
    const float* b2  = (const float*)d_in[8];
    const float* W2r = (const float*)d_in[9];

    const int N = in_sizes[0];        // 200000
    const int E = in_sizes[1] / 2;    // 6400000
    float* out = (float*)d_out;       // [512]

    const int pp   = 20;                                      // dst parts
    const int bins = (N + pp - 1) / pp;                       // 10000 (exact)
    const int nc   = pp * NSB;                                // 500 cells
    const unsigned Mdiv =
        (unsigned)(((1ULL << 32) + (unsigned)bins - 1) / (unsigned)bins);

    // workspace (u32 words): pairs[nc*NBLK*RING] | slab[NSB][N] | pvq[N] |
    // zd[N] | xq1[N] | blockCnt[nc*NBLK] | ovf[OVFCAP u64] |
    // ovfTail[16] | outq[512 u64]
    unsigned* pairs = (unsigned*)d_ws;
    unsigned* slab1 = pairs + (size_t)nc * NBLK * RING;       // 16,384,000
    int*      pvq   = (int*)(slab1 + (size_t)NSB * N);
    unsigned* zd    = (unsigned*)(pvq + N);
    unsigned* xq1   = zd + N;
    unsigned* blockCnt = xq1 + N;
    unsigned long long* ovf =
        (unsigned long long*)(blockCnt + (size_t)nc * NBLK);
    unsigned* ovfTail = (unsigned*)(ovf + OVFCAP);
    unsigned long long* outq = (unsigned long long*)(ovfTail + 16);

    hipMemsetAsync(d_out, 0, (size_t)out_size * sizeof(float), stream);
    hipMemsetAsync(ovfTail, 0, (16 + 1024) * sizeof(unsigned), stream);

    const int partShmem = nc * RING * 4;                // 128000 B
    const int binShmem  = (8192 + bins) * 4;            // 72768 B
    const int poolShmem = (8192 + bins) * 4 + 512 * 8;  // 76864 B
    hipFuncSetAttribute((const void*)partition_kernel,
                        hipFuncAttributeMaxDynamicSharedMemorySize, partShmem);
    hipFuncSetAttribute((const void*)bin1_kernel,
                        hipFuncAttributeMaxDynamicSharedMemorySize, binShmem);
    hipFuncSetAttribute((const void*)pool_kernel,
                        hipFuncAttributeMaxDynamicSharedMemorySize, poolShmem);

    const int NB = 256;
    int node_blocks = (N + NB - 1) / NB;

    partition_kernel<<<NBLK, BLK, partShmem, stream>>>(ei, x, xq1, pairs,
                                                       blockCnt, ovf, ovfTail,
                                                       E, N, bins, Mdiv, nc);
    bin1_kernel<<<nc, BLK, binShmem, stream>>>(pairs, blockCnt, ovf, ovfTail,
                                               xq1, slab1, N, bins);
    node_pass1_kernel<<<node_blocks, NB, 0, stream>>>(x, slab1, W1l, b1, W1r,
                                                      W2l, W2r, b2, batch,
                                                      pvq, zd, out, N);
    pool_kernel<<<nc, BLK, poolShmem, stream>>>(pairs, blockCnt, ovf, ovfTail,
                                                pvq, zd, outq, N, bins);
    finalize_kernel<<<(out_size + 255) / 256, 256, 0, stream>>>(outq, out,
                                                                out_size);
}